// Round 1
// baseline (168.689 us; speedup 1.0000x reference)
//
#include <hip/hip_runtime.h>
#include <math.h>

#define MAXF   32
#define FTOUT  512
#define VFT    768

__global__ __launch_bounds__(256)
void nnhalfka_fused(const int* __restrict__ stm_idx,    // [2, nnz]
                    const int* __restrict__ nstm_idx,   // [2, nnz]
                    const float* __restrict__ values,   // [nnz]
                    const float* __restrict__ W_ft,     // [49152, 512]
                    const float* __restrict__ b_ft,     // [512]
                    const float* __restrict__ W_fft,    // [768, 512]
                    const float* __restrict__ b_fft,    // [512]
                    const float* __restrict__ W_out,    // [1024]
                    const float* __restrict__ b_out,    // [1]
                    float* __restrict__ out,            // [batch]
                    int nnz)
{
    const int b   = blockIdx.x;
    const int tid = threadIdx.x;

    __shared__ int   s_fs[MAXF], s_fsm[MAXF], s_fn[MAXF], s_fnm[MAXF];
    __shared__ float s_v[MAXF];
    __shared__ float s_red[4];

    if (tid < MAXF) {
        const int g  = b * MAXF + tid;
        const int fs = stm_idx[nnz + g];     // row 1 = feature ids
        const int fn = nstm_idx[nnz + g];
        s_fs[tid]  = fs * FTOUT;
        s_fsm[tid] = (fs % VFT) * FTOUT;
        s_fn[tid]  = fn * FTOUT;
        s_fnm[tid] = (fn % VFT) * FTOUT;
        s_v[tid]   = values[g];
    }
    __syncthreads();

    const int j = tid * 2;                   // 256 threads x float2 = 512 feats
    float2 accs = make_float2(0.f, 0.f);
    float2 accn = make_float2(0.f, 0.f);

    #pragma unroll 4
    for (int k = 0; k < MAXF; ++k) {
        const float v   = s_v[k];
        const float2 ws  = *(const float2*)(W_ft  + s_fs[k]  + j);
        const float2 wfs = *(const float2*)(W_fft + s_fsm[k] + j);
        const float2 wn  = *(const float2*)(W_ft  + s_fn[k]  + j);
        const float2 wfn = *(const float2*)(W_fft + s_fnm[k] + j);
        accs.x += v * (ws.x + wfs.x);
        accs.y += v * (ws.y + wfs.y);
        accn.x += v * (wn.x + wfn.x);
        accn.y += v * (wn.y + wfn.y);
    }

    const float bb0 = b_ft[j]     + b_fft[j];
    const float bb1 = b_ft[j + 1] + b_fft[j + 1];

    const float hs0 = fminf(fmaxf(accs.x + bb0, 0.f), 1.f);
    const float hs1 = fminf(fmaxf(accs.y + bb1, 0.f), 1.f);
    const float hn0 = fminf(fmaxf(accn.x + bb0, 0.f), 1.f);
    const float hn1 = fminf(fmaxf(accn.y + bb1, 0.f), 1.f);

    float partial = hs0 * W_out[j]         + hs1 * W_out[j + 1]
                  + hn0 * W_out[FTOUT + j] + hn1 * W_out[FTOUT + j + 1];

    // wave-64 reduction
    #pragma unroll
    for (int off = 32; off > 0; off >>= 1)
        partial += __shfl_down(partial, off);

    if ((tid & 63) == 0) s_red[tid >> 6] = partial;
    __syncthreads();

    if (tid == 0) {
        const float tot = s_red[0] + s_red[1] + s_red[2] + s_red[3] + b_out[0];
        out[b] = 1.0f / (1.0f + expf(-tot));
    }
}

extern "C" void kernel_launch(void* const* d_in, const int* in_sizes, int n_in,
                              void* d_out, int out_size, void* d_ws, size_t ws_size,
                              hipStream_t stream) {
    const int*   stm_idx  = (const int*)d_in[0];
    const int*   nstm_idx = (const int*)d_in[1];
    const float* values   = (const float*)d_in[2];
    // d_in[3] = size scalar (8192) — batch comes from out_size
    const float* W_ft     = (const float*)d_in[4];
    const float* b_ft     = (const float*)d_in[5];
    const float* W_fft    = (const float*)d_in[6];
    const float* b_fft    = (const float*)d_in[7];
    const float* W_out    = (const float*)d_in[8];
    const float* b_out    = (const float*)d_in[9];
    float* out = (float*)d_out;

    const int nnz   = in_sizes[0] / 2;   // [2, nnz]
    const int batch = out_size;          // 8192

    nnhalfka_fused<<<batch, 256, 0, stream>>>(
        stm_idx, nstm_idx, values, W_ft, b_ft, W_fft, b_fft, W_out, b_out,
        out, nnz);
}

// Round 2
// 105.229 us; speedup vs baseline: 1.6031x; 1.6031x over previous
//
#include <hip/hip_runtime.h>
#include <math.h>

#define MAXF   32
#define FTOUT  512
#define VFT    768
#define FTIN   49152

// ---------------------------------------------------------------------------
// Kernel 1: Wsum[f][j] = bf16_rne( W_ft[f][j] + W_fft[f % 768][j] )
// ---------------------------------------------------------------------------
__global__ __launch_bounds__(256)
void build_wsum(const float* __restrict__ W_ft,
                const float* __restrict__ W_fft,
                unsigned short* __restrict__ Wsum)
{
    const long long e = ((long long)blockIdx.x * blockDim.x + threadIdx.x) * 4;
    const int f = (int)(e >> 9);          // e / 512
    const int j = (int)(e & 511);
    const float4 a = *(const float4*)(W_ft + e);
    const float4 c = *(const float4*)(W_fft + (long long)(f % VFT) * FTOUT + j);
    const float s[4] = {a.x + c.x, a.y + c.y, a.z + c.z, a.w + c.w};
    ushort4 o;
    unsigned short* op = (unsigned short*)&o;
    #pragma unroll
    for (int t = 0; t < 4; ++t) {
        unsigned int u = __float_as_uint(s[t]);
        u += 0x7FFFu + ((u >> 16) & 1u);      // round-to-nearest-even
        op[t] = (unsigned short)(u >> 16);
    }
    *(ushort4*)(Wsum + e) = o;
}

// ---------------------------------------------------------------------------
// Kernel 2: per batch row, 2 waves (stm / nstm). Each wave: 32 gathers of a
// full 512-feat bf16 row (64 lanes x 16B), accumulate f32, clip, dot W_out.
// ---------------------------------------------------------------------------
__global__ __launch_bounds__(128)
void nnhalfka_gather(const int* __restrict__ stm_idx,
                     const int* __restrict__ nstm_idx,
                     const float* __restrict__ values,
                     const unsigned short* __restrict__ Wsum,
                     const float* __restrict__ b_ft,
                     const float* __restrict__ b_fft,
                     const float* __restrict__ W_out,
                     const float* __restrict__ b_out,
                     float* __restrict__ out,
                     int nnz)
{
    const int b    = blockIdx.x;
    const int tid  = threadIdx.x;
    const int wave = tid >> 6;     // 0 = stm, 1 = nstm
    const int lane = tid & 63;

    __shared__ int   s_off[2][MAXF];
    __shared__ float s_v[MAXF];
    __shared__ float s_red[2];

    if (lane < MAXF) {
        const int g = b * MAXF + lane;
        const int* src = wave ? nstm_idx : stm_idx;
        s_off[wave][lane] = src[nnz + g] * FTOUT;   // bf16-element offset
    } else if (wave == 0) {
        s_v[lane - MAXF] = values[b * MAXF + (lane - MAXF)];
    }
    __syncthreads();

    const int jbase = lane * 8;    // 8 consecutive bf16 feats per lane
    float acc[8] = {0.f, 0.f, 0.f, 0.f, 0.f, 0.f, 0.f, 0.f};

    #pragma unroll 8
    for (int k = 0; k < MAXF; ++k) {
        const float v = s_v[k];
        const uint4 w = *(const uint4*)(Wsum + s_off[wave][k] + jbase);
        const unsigned int* wp = (const unsigned int*)&w;
        #pragma unroll
        for (int t = 0; t < 4; ++t) {
            const float lo = __uint_as_float(wp[t] << 16);
            const float hi = __uint_as_float(wp[t] & 0xFFFF0000u);
            acc[2 * t]     = fmaf(v, lo, acc[2 * t]);
            acc[2 * t + 1] = fmaf(v, hi, acc[2 * t + 1]);
        }
    }

    // bias + clip + W_out dot for this lane's 8 features
    float bb[8], wo[8];
    *(float4*)&bb[0] = *(const float4*)(b_ft + jbase);
    *(float4*)&bb[4] = *(const float4*)(b_ft + jbase + 4);
    {
        const float4 v0 = *(const float4*)(b_fft + jbase);
        const float4 v1 = *(const float4*)(b_fft + jbase + 4);
        bb[0] += v0.x; bb[1] += v0.y; bb[2] += v0.z; bb[3] += v0.w;
        bb[4] += v1.x; bb[5] += v1.y; bb[6] += v1.z; bb[7] += v1.w;
    }
    *(float4*)&wo[0] = *(const float4*)(W_out + wave * FTOUT + jbase);
    *(float4*)&wo[4] = *(const float4*)(W_out + wave * FTOUT + jbase + 4);

    float partial = 0.f;
    #pragma unroll
    for (int t = 0; t < 8; ++t) {
        const float h = fminf(fmaxf(acc[t] + bb[t], 0.f), 1.f);
        partial = fmaf(h, wo[t], partial);
    }

    #pragma unroll
    for (int off = 32; off > 0; off >>= 1)
        partial += __shfl_down(partial, off);

    if (lane == 0) s_red[wave] = partial;
    __syncthreads();

    if (tid == 0) {
        const float tot = s_red[0] + s_red[1] + b_out[0];
        out[b] = 1.0f / (1.0f + expf(-tot));
    }
}

// ---------------------------------------------------------------------------
// Fallback (round-1 kernel) if ws_size can't hold the 50 MB bf16 table.
// ---------------------------------------------------------------------------
__global__ __launch_bounds__(256)
void nnhalfka_fused(const int* __restrict__ stm_idx,
                    const int* __restrict__ nstm_idx,
                    const float* __restrict__ values,
                    const float* __restrict__ W_ft,
                    const float* __restrict__ b_ft,
                    const float* __restrict__ W_fft,
                    const float* __restrict__ b_fft,
                    const float* __restrict__ W_out,
                    const float* __restrict__ b_out,
                    float* __restrict__ out,
                    int nnz)
{
    const int b   = blockIdx.x;
    const int tid = threadIdx.x;

    __shared__ int   s_fs[MAXF], s_fsm[MAXF], s_fn[MAXF], s_fnm[MAXF];
    __shared__ float s_v[MAXF];
    __shared__ float s_red[4];

    if (tid < MAXF) {
        const int g  = b * MAXF + tid;
        const int fs = stm_idx[nnz + g];
        const int fn = nstm_idx[nnz + g];
        s_fs[tid]  = fs * FTOUT;
        s_fsm[tid] = (fs % VFT) * FTOUT;
        s_fn[tid]  = fn * FTOUT;
        s_fnm[tid] = (fn % VFT) * FTOUT;
        s_v[tid]   = values[g];
    }
    __syncthreads();

    const int j = tid * 2;
    float2 accs = make_float2(0.f, 0.f);
    float2 accn = make_float2(0.f, 0.f);

    #pragma unroll 4
    for (int k = 0; k < MAXF; ++k) {
        const float v   = s_v[k];
        const float2 ws  = *(const float2*)(W_ft  + s_fs[k]  + j);
        const float2 wfs = *(const float2*)(W_fft + s_fsm[k] + j);
        const float2 wn  = *(const float2*)(W_ft  + s_fn[k]  + j);
        const float2 wfn = *(const float2*)(W_fft + s_fnm[k] + j);
        accs.x += v * (ws.x + wfs.x);
        accs.y += v * (ws.y + wfs.y);
        accn.x += v * (wn.x + wfn.x);
        accn.y += v * (wn.y + wfn.y);
    }

    const float bb0 = b_ft[j]     + b_fft[j];
    const float bb1 = b_ft[j + 1] + b_fft[j + 1];

    const float hs0 = fminf(fmaxf(accs.x + bb0, 0.f), 1.f);
    const float hs1 = fminf(fmaxf(accs.y + bb1, 0.f), 1.f);
    const float hn0 = fminf(fmaxf(accn.x + bb0, 0.f), 1.f);
    const float hn1 = fminf(fmaxf(accn.y + bb1, 0.f), 1.f);

    float partial = hs0 * W_out[j]         + hs1 * W_out[j + 1]
                  + hn0 * W_out[FTOUT + j] + hn1 * W_out[FTOUT + j + 1];

    #pragma unroll
    for (int off = 32; off > 0; off >>= 1)
        partial += __shfl_down(partial, off);

    if ((tid & 63) == 0) s_red[tid >> 6] = partial;
    __syncthreads();

    if (tid == 0) {
        const float tot = s_red[0] + s_red[1] + s_red[2] + s_red[3] + b_out[0];
        out[b] = 1.0f / (1.0f + expf(-tot));
    }
}

extern "C" void kernel_launch(void* const* d_in, const int* in_sizes, int n_in,
                              void* d_out, int out_size, void* d_ws, size_t ws_size,
                              hipStream_t stream) {
    const int*   stm_idx  = (const int*)d_in[0];
    const int*   nstm_idx = (const int*)d_in[1];
    const float* values   = (const float*)d_in[2];
    const float* W_ft     = (const float*)d_in[4];
    const float* b_ft     = (const float*)d_in[5];
    const float* W_fft    = (const float*)d_in[6];
    const float* b_fft    = (const float*)d_in[7];
    const float* W_out    = (const float*)d_in[8];
    const float* b_out    = (const float*)d_in[9];
    float* out = (float*)d_out;

    const int nnz   = in_sizes[0] / 2;
    const int batch = out_size;

    const size_t wsum_bytes = (size_t)FTIN * FTOUT * sizeof(unsigned short);
    if (ws_size >= wsum_bytes) {
        unsigned short* Wsum = (unsigned short*)d_ws;
        build_wsum<<<(FTIN * FTOUT / 4) / 256, 256, 0, stream>>>(W_ft, W_fft, Wsum);
        nnhalfka_gather<<<batch, 128, 0, stream>>>(
            stm_idx, nstm_idx, values, Wsum, b_ft, b_fft, W_out, b_out, out, nnz);
    } else {
        nnhalfka_fused<<<batch, 256, 0, stream>>>(
            stm_idx, nstm_idx, values, W_ft, b_ft, W_fft, b_fft, W_out, b_out,
            out, nnz);
    }
}

// Round 3
// 101.058 us; speedup vs baseline: 1.6692x; 1.0413x over previous
//
#include <hip/hip_runtime.h>
#include <math.h>

#define MAXF   32
#define FTOUT  512
#define VFT    768
#define FTIN   49152

// ---------------------------------------------------------------------------
// Kernel 1: Wsum[f][j] = bf16_rne( W_ft[f][j] + W_fft[f % 768][j] )
// ---------------------------------------------------------------------------
__global__ __launch_bounds__(256)
void build_wsum(const float* __restrict__ W_ft,
                const float* __restrict__ W_fft,
                unsigned short* __restrict__ Wsum)
{
    const long long e = ((long long)blockIdx.x * blockDim.x + threadIdx.x) * 4;
    const int f = (int)(e >> 9);          // e / 512
    const int j = (int)(e & 511);
    const float4 a = *(const float4*)(W_ft + e);
    const float4 c = *(const float4*)(W_fft + (long long)(f % VFT) * FTOUT + j);
    const float s[4] = {a.x + c.x, a.y + c.y, a.z + c.z, a.w + c.w};
    ushort4 o;
    unsigned short* op = (unsigned short*)&o;
    #pragma unroll
    for (int t = 0; t < 4; ++t) {
        unsigned int u = __float_as_uint(s[t]);
        u += 0x7FFFu + ((u >> 16) & 1u);      // round-to-nearest-even
        op[t] = (unsigned short)(u >> 16);
    }
    *(ushort4*)(Wsum + e) = o;
}

// ---------------------------------------------------------------------------
// Kernel 2: per batch row, 2 waves (stm / nstm). Each wave: 32 gathers of a
// full 512-feat bf16 row (64 lanes x 16B). Loads issued in groups of 8 into
// named registers for deep MLP (VGPR ~56, still 32 waves/CU).
// ---------------------------------------------------------------------------
__global__ __launch_bounds__(128, 8)
void nnhalfka_gather(const int* __restrict__ stm_idx,
                     const int* __restrict__ nstm_idx,
                     const float* __restrict__ values,
                     const unsigned short* __restrict__ Wsum,
                     const float* __restrict__ b_ft,
                     const float* __restrict__ b_fft,
                     const float* __restrict__ W_out,
                     const float* __restrict__ b_out,
                     float* __restrict__ out,
                     int nnz)
{
    const int b    = blockIdx.x;
    const int tid  = threadIdx.x;
    const int wave = tid >> 6;     // 0 = stm, 1 = nstm
    const int lane = tid & 63;

    __shared__ int   s_off[2][MAXF];
    __shared__ float s_v[MAXF];
    __shared__ float s_red[2];

    if (lane < MAXF) {
        const int g = b * MAXF + lane;
        const int* src = wave ? nstm_idx : stm_idx;
        s_off[wave][lane] = src[nnz + g] * FTOUT;   // bf16-element offset
    } else if (wave == 0) {
        s_v[lane - MAXF] = values[b * MAXF + (lane - MAXF)];
    }
    __syncthreads();

    const int jbase = lane * 8;    // 8 consecutive bf16 feats per lane
    float acc[8] = {0.f, 0.f, 0.f, 0.f, 0.f, 0.f, 0.f, 0.f};

    #pragma unroll
    for (int g8 = 0; g8 < MAXF / 8; ++g8) {
        // issue 8 independent 1KB gathers back-to-back (static regs)
        uint4 w0 = *(const uint4*)(Wsum + s_off[wave][g8 * 8 + 0] + jbase);
        uint4 w1 = *(const uint4*)(Wsum + s_off[wave][g8 * 8 + 1] + jbase);
        uint4 w2 = *(const uint4*)(Wsum + s_off[wave][g8 * 8 + 2] + jbase);
        uint4 w3 = *(const uint4*)(Wsum + s_off[wave][g8 * 8 + 3] + jbase);
        uint4 w4 = *(const uint4*)(Wsum + s_off[wave][g8 * 8 + 4] + jbase);
        uint4 w5 = *(const uint4*)(Wsum + s_off[wave][g8 * 8 + 5] + jbase);
        uint4 w6 = *(const uint4*)(Wsum + s_off[wave][g8 * 8 + 6] + jbase);
        uint4 w7 = *(const uint4*)(Wsum + s_off[wave][g8 * 8 + 7] + jbase);

        const uint4* wbuf[8] = {&w0, &w1, &w2, &w3, &w4, &w5, &w6, &w7};
        #pragma unroll
        for (int t = 0; t < 8; ++t) {
            const float v = s_v[g8 * 8 + t];
            const unsigned int* wp = (const unsigned int*)wbuf[t];
            #pragma unroll
            for (int q = 0; q < 4; ++q) {
                const float lo = __uint_as_float(wp[q] << 16);
                const float hi = __uint_as_float(wp[q] & 0xFFFF0000u);
                acc[2 * q]     = fmaf(v, lo, acc[2 * q]);
                acc[2 * q + 1] = fmaf(v, hi, acc[2 * q + 1]);
            }
        }
    }

    // bias + clip + W_out dot for this lane's 8 features
    float bb[8], wo[8];
    *(float4*)&bb[0] = *(const float4*)(b_ft + jbase);
    *(float4*)&bb[4] = *(const float4*)(b_ft + jbase + 4);
    {
        const float4 v0 = *(const float4*)(b_fft + jbase);
        const float4 v1 = *(const float4*)(b_fft + jbase + 4);
        bb[0] += v0.x; bb[1] += v0.y; bb[2] += v0.z; bb[3] += v0.w;
        bb[4] += v1.x; bb[5] += v1.y; bb[6] += v1.z; bb[7] += v1.w;
    }
    *(float4*)&wo[0] = *(const float4*)(W_out + wave * FTOUT + jbase);
    *(float4*)&wo[4] = *(const float4*)(W_out + wave * FTOUT + jbase + 4);

    float partial = 0.f;
    #pragma unroll
    for (int t = 0; t < 8; ++t) {
        const float h = fminf(fmaxf(acc[t] + bb[t], 0.f), 1.f);
        partial = fmaf(h, wo[t], partial);
    }

    #pragma unroll
    for (int off = 32; off > 0; off >>= 1)
        partial += __shfl_down(partial, off);

    if (lane == 0) s_red[wave] = partial;
    __syncthreads();

    if (tid == 0) {
        const float tot = s_red[0] + s_red[1] + b_out[0];
        out[b] = 1.0f / (1.0f + expf(-tot));
    }
}

// ---------------------------------------------------------------------------
// Fallback (round-1 kernel) if ws_size can't hold the 50 MB bf16 table.
// ---------------------------------------------------------------------------
__global__ __launch_bounds__(256)
void nnhalfka_fused(const int* __restrict__ stm_idx,
                    const int* __restrict__ nstm_idx,
                    const float* __restrict__ values,
                    const float* __restrict__ W_ft,
                    const float* __restrict__ b_ft,
                    const float* __restrict__ W_fft,
                    const float* __restrict__ b_fft,
                    const float* __restrict__ W_out,
                    const float* __restrict__ b_out,
                    float* __restrict__ out,
                    int nnz)
{
    const int b   = blockIdx.x;
    const int tid = threadIdx.x;

    __shared__ int   s_fs[MAXF], s_fsm[MAXF], s_fn[MAXF], s_fnm[MAXF];
    __shared__ float s_v[MAXF];
    __shared__ float s_red[4];

    if (tid < MAXF) {
        const int g  = b * MAXF + tid;
        const int fs = stm_idx[nnz + g];
        const int fn = nstm_idx[nnz + g];
        s_fs[tid]  = fs * FTOUT;
        s_fsm[tid] = (fs % VFT) * FTOUT;
        s_fn[tid]  = fn * FTOUT;
        s_fnm[tid] = (fn % VFT) * FTOUT;
        s_v[tid]   = values[g];
    }
    __syncthreads();

    const int j = tid * 2;
    float2 accs = make_float2(0.f, 0.f);
    float2 accn = make_float2(0.f, 0.f);

    #pragma unroll 4
    for (int k = 0; k < MAXF; ++k) {
        const float v   = s_v[k];
        const float2 ws  = *(const float2*)(W_ft  + s_fs[k]  + j);
        const float2 wfs = *(const float2*)(W_fft + s_fsm[k] + j);
        const float2 wn  = *(const float2*)(W_ft  + s_fn[k]  + j);
        const float2 wfn = *(const float2*)(W_fft + s_fnm[k] + j);
        accs.x += v * (ws.x + wfs.x);
        accs.y += v * (ws.y + wfs.y);
        accn.x += v * (wn.x + wfn.x);
        accn.y += v * (wn.y + wfn.y);
    }

    const float bb0 = b_ft[j]     + b_fft[j];
    const float bb1 = b_ft[j + 1] + b_fft[j + 1];

    const float hs0 = fminf(fmaxf(accs.x + bb0, 0.f), 1.f);
    const float hs1 = fminf(fmaxf(accs.y + bb1, 0.f), 1.f);
    const float hn0 = fminf(fmaxf(accn.x + bb0, 0.f), 1.f);
    const float hn1 = fminf(fmaxf(accn.y + bb1, 0.f), 1.f);

    float partial = hs0 * W_out[j]         + hs1 * W_out[j + 1]
                  + hn0 * W_out[FTOUT + j] + hn1 * W_out[FTOUT + j + 1];

    #pragma unroll
    for (int off = 32; off > 0; off >>= 1)
        partial += __shfl_down(partial, off);

    if ((tid & 63) == 0) s_red[tid >> 6] = partial;
    __syncthreads();

    if (tid == 0) {
        const float tot = s_red[0] + s_red[1] + s_red[2] + s_red[3] + b_out[0];
        out[b] = 1.0f / (1.0f + expf(-tot));
    }
}

extern "C" void kernel_launch(void* const* d_in, const int* in_sizes, int n_in,
                              void* d_out, int out_size, void* d_ws, size_t ws_size,
                              hipStream_t stream) {
    const int*   stm_idx  = (const int*)d_in[0];
    const int*   nstm_idx = (const int*)d_in[1];
    const float* values   = (const float*)d_in[2];
    const float* W_ft     = (const float*)d_in[4];
    const float* b_ft     = (const float*)d_in[5];
    const float* W_fft    = (const float*)d_in[6];
    const float* b_fft    = (const float*)d_in[7];
    const float* W_out    = (const float*)d_in[8];
    const float* b_out    = (const float*)d_in[9];
    float* out = (float*)d_out;

    const int nnz   = in_sizes[0] / 2;
    const int batch = out_size;

    const size_t wsum_bytes = (size_t)FTIN * FTOUT * sizeof(unsigned short);
    if (ws_size >= wsum_bytes) {
        unsigned short* Wsum = (unsigned short*)d_ws;
        build_wsum<<<(FTIN * FTOUT / 4) / 256, 256, 0, stream>>>(W_ft, W_fft, Wsum);
        nnhalfka_gather<<<batch, 128, 0, stream>>>(
            stm_idx, nstm_idx, values, Wsum, b_ft, b_fft, W_out, b_out, out, nnz);
    } else {
        nnhalfka_fused<<<batch, 256, 0, stream>>>(
            stm_idx, nstm_idx, values, W_ft, b_ft, W_fft, b_fft, W_out, b_out,
            out, nnz);
    }
}

// Round 4
// 98.993 us; speedup vs baseline: 1.7040x; 1.0209x over previous
//
#include <hip/hip_runtime.h>
#include <math.h>

#define MAXF   32
#define FTOUT  512
#define VFT    768
#define FTIN   49152

// ---------------------------------------------------------------------------
// Kernel 1: Wsum[f][j] = bf16_rne( W_ft[f][j] + W_fft[f % 768][j] )
// ---------------------------------------------------------------------------
__global__ __launch_bounds__(256)
void build_wsum(const float* __restrict__ W_ft,
                const float* __restrict__ W_fft,
                unsigned short* __restrict__ Wsum)
{
    const long long e = ((long long)blockIdx.x * blockDim.x + threadIdx.x) * 4;
    const int f = (int)(e >> 9);          // e / 512
    const int j = (int)(e & 511);
    const float4 a = *(const float4*)(W_ft + e);
    const float4 c = *(const float4*)(W_fft + (long long)(f % VFT) * FTOUT + j);
    const float s[4] = {a.x + c.x, a.y + c.y, a.z + c.z, a.w + c.w};
    ushort4 o;
    unsigned short* op = (unsigned short*)&o;
    #pragma unroll
    for (int t = 0; t < 4; ++t) {
        unsigned int u = __float_as_uint(s[t]);
        u += 0x7FFFu + ((u >> 16) & 1u);      // round-to-nearest-even
        op[t] = (unsigned short)(u >> 16);
    }
    *(ushort4*)(Wsum + e) = o;
}

// ---------------------------------------------------------------------------
// Kernel 2: 4 waves/block: (perspective, k-half). Each wave issues 16
// independent 1KB row gathers (named regs, pinned by sched_barrier) then
// consumes. Halves combined via padded LDS before clip+dot.
// ---------------------------------------------------------------------------
__global__ __launch_bounds__(256, 4)
void nnhalfka_gather(const int* __restrict__ stm_idx,
                     const int* __restrict__ nstm_idx,
                     const float* __restrict__ values,
                     const unsigned short* __restrict__ Wsum,
                     const float* __restrict__ b_ft,
                     const float* __restrict__ b_fft,
                     const float* __restrict__ W_out,
                     const float* __restrict__ b_out,
                     float* __restrict__ out,
                     int nnz)
{
    const int b     = blockIdx.x;
    const int tid   = threadIdx.x;
    const int wid   = tid >> 6;      // 0..3
    const int lane  = tid & 63;
    const int persp = wid >> 1;      // 0 = stm, 1 = nstm
    const int half  = wid & 1;       // k-range half

    __shared__ int   s_off[2][MAXF];
    __shared__ float s_v[MAXF];
    __shared__ float s_acc[2][64][9];   // +1 pad: conflict-free stride
    __shared__ float s_red[2];

    if (tid < MAXF) {
        const int g = b * MAXF + tid;
        s_off[0][tid] = stm_idx[nnz + g] * FTOUT;
        s_v[tid]      = values[g];
    } else if (tid >= 64 && tid < 64 + MAXF) {
        const int t = tid - 64;
        s_off[1][t] = nstm_idx[nnz + b * MAXF + t] * FTOUT;
    }
    __syncthreads();

    const int jbase = lane * 8;               // 8 bf16 feats per lane
    const unsigned short* bp = Wsum + jbase;
    const int k0 = half * 16;

    float acc[8] = {0.f, 0.f, 0.f, 0.f, 0.f, 0.f, 0.f, 0.f};

    // ---- issue 16 independent gathers into named registers ----
    uint4 a0 = *(const uint4*)(bp + s_off[persp][k0 + 0]);
    uint4 a1 = *(const uint4*)(bp + s_off[persp][k0 + 1]);
    uint4 a2 = *(const uint4*)(bp + s_off[persp][k0 + 2]);
    uint4 a3 = *(const uint4*)(bp + s_off[persp][k0 + 3]);
    uint4 a4 = *(const uint4*)(bp + s_off[persp][k0 + 4]);
    uint4 a5 = *(const uint4*)(bp + s_off[persp][k0 + 5]);
    uint4 a6 = *(const uint4*)(bp + s_off[persp][k0 + 6]);
    uint4 a7 = *(const uint4*)(bp + s_off[persp][k0 + 7]);
    uint4 c0 = *(const uint4*)(bp + s_off[persp][k0 + 8]);
    uint4 c1 = *(const uint4*)(bp + s_off[persp][k0 + 9]);
    uint4 c2 = *(const uint4*)(bp + s_off[persp][k0 + 10]);
    uint4 c3 = *(const uint4*)(bp + s_off[persp][k0 + 11]);
    uint4 c4 = *(const uint4*)(bp + s_off[persp][k0 + 12]);
    uint4 c5 = *(const uint4*)(bp + s_off[persp][k0 + 13]);
    uint4 c6 = *(const uint4*)(bp + s_off[persp][k0 + 14]);
    uint4 c7 = *(const uint4*)(bp + s_off[persp][k0 + 15]);
    __builtin_amdgcn_sched_barrier(0);   // keep all 16 in flight

    auto cons = [&acc](const uint4 w, const float v) {
        acc[0] = fmaf(v, __uint_as_float(w.x << 16),         acc[0]);
        acc[1] = fmaf(v, __uint_as_float(w.x & 0xFFFF0000u), acc[1]);
        acc[2] = fmaf(v, __uint_as_float(w.y << 16),         acc[2]);
        acc[3] = fmaf(v, __uint_as_float(w.y & 0xFFFF0000u), acc[3]);
        acc[4] = fmaf(v, __uint_as_float(w.z << 16),         acc[4]);
        acc[5] = fmaf(v, __uint_as_float(w.z & 0xFFFF0000u), acc[5]);
        acc[6] = fmaf(v, __uint_as_float(w.w << 16),         acc[6]);
        acc[7] = fmaf(v, __uint_as_float(w.w & 0xFFFF0000u), acc[7]);
    };

    cons(a0, s_v[k0 + 0]);  cons(a1, s_v[k0 + 1]);
    cons(a2, s_v[k0 + 2]);  cons(a3, s_v[k0 + 3]);
    cons(a4, s_v[k0 + 4]);  cons(a5, s_v[k0 + 5]);
    cons(a6, s_v[k0 + 6]);  cons(a7, s_v[k0 + 7]);
    cons(c0, s_v[k0 + 8]);  cons(c1, s_v[k0 + 9]);
    cons(c2, s_v[k0 + 10]); cons(c3, s_v[k0 + 11]);
    cons(c4, s_v[k0 + 12]); cons(c5, s_v[k0 + 13]);
    cons(c6, s_v[k0 + 14]); cons(c7, s_v[k0 + 15]);

    // ---- combine halves, clip, dot ----
    if (half) {
        #pragma unroll
        for (int t = 0; t < 8; ++t) s_acc[persp][lane][t] = acc[t];
    }
    __syncthreads();

    if (!half) {
        float bb[8], wo[8];
        *(float4*)&bb[0] = *(const float4*)(b_ft + jbase);
        *(float4*)&bb[4] = *(const float4*)(b_ft + jbase + 4);
        {
            const float4 v0 = *(const float4*)(b_fft + jbase);
            const float4 v1 = *(const float4*)(b_fft + jbase + 4);
            bb[0] += v0.x; bb[1] += v0.y; bb[2] += v0.z; bb[3] += v0.w;
            bb[4] += v1.x; bb[5] += v1.y; bb[6] += v1.z; bb[7] += v1.w;
        }
        *(float4*)&wo[0] = *(const float4*)(W_out + persp * FTOUT + jbase);
        *(float4*)&wo[4] = *(const float4*)(W_out + persp * FTOUT + jbase + 4);

        float partial = 0.f;
        #pragma unroll
        for (int t = 0; t < 8; ++t) {
            const float s = acc[t] + s_acc[persp][lane][t];
            const float h = fminf(fmaxf(s + bb[t], 0.f), 1.f);
            partial = fmaf(h, wo[t], partial);
        }

        #pragma unroll
        for (int off = 32; off > 0; off >>= 1)
            partial += __shfl_down(partial, off);

        if (lane == 0) s_red[persp] = partial;
    }
    __syncthreads();

    if (tid == 0) {
        const float tot = s_red[0] + s_red[1] + b_out[0];
        out[b] = 1.0f / (1.0f + expf(-tot));
    }
}

// ---------------------------------------------------------------------------
// Fallback (round-1 kernel) if ws_size can't hold the 48 MB bf16 table.
// ---------------------------------------------------------------------------
__global__ __launch_bounds__(256)
void nnhalfka_fused(const int* __restrict__ stm_idx,
                    const int* __restrict__ nstm_idx,
                    const float* __restrict__ values,
                    const float* __restrict__ W_ft,
                    const float* __restrict__ b_ft,
                    const float* __restrict__ W_fft,
                    const float* __restrict__ b_fft,
                    const float* __restrict__ W_out,
                    const float* __restrict__ b_out,
                    float* __restrict__ out,
                    int nnz)
{
    const int b   = blockIdx.x;
    const int tid = threadIdx.x;

    __shared__ int   s_fs[MAXF], s_fsm[MAXF], s_fn[MAXF], s_fnm[MAXF];
    __shared__ float s_v[MAXF];
    __shared__ float s_red[4];

    if (tid < MAXF) {
        const int g  = b * MAXF + tid;
        const int fs = stm_idx[nnz + g];
        const int fn = nstm_idx[nnz + g];
        s_fs[tid]  = fs * FTOUT;
        s_fsm[tid] = (fs % VFT) * FTOUT;
        s_fn[tid]  = fn * FTOUT;
        s_fnm[tid] = (fn % VFT) * FTOUT;
        s_v[tid]   = values[g];
    }
    __syncthreads();

    const int j = tid * 2;
    float2 accs = make_float2(0.f, 0.f);
    float2 accn = make_float2(0.f, 0.f);

    #pragma unroll 4
    for (int k = 0; k < MAXF; ++k) {
        const float v   = s_v[k];
        const float2 ws  = *(const float2*)(W_ft  + s_fs[k]  + j);
        const float2 wfs = *(const float2*)(W_fft + s_fsm[k] + j);
        const float2 wn  = *(const float2*)(W_ft  + s_fn[k]  + j);
        const float2 wfn = *(const float2*)(W_fft + s_fnm[k] + j);
        accs.x += v * (ws.x + wfs.x);
        accs.y += v * (ws.y + wfs.y);
        accn.x += v * (wn.x + wfn.x);
        accn.y += v * (wn.y + wfn.y);
    }

    const float bb0 = b_ft[j]     + b_fft[j];
    const float bb1 = b_ft[j + 1] + b_fft[j + 1];

    const float hs0 = fminf(fmaxf(accs.x + bb0, 0.f), 1.f);
    const float hs1 = fminf(fmaxf(accs.y + bb1, 0.f), 1.f);
    const float hn0 = fminf(fmaxf(accn.x + bb0, 0.f), 1.f);
    const float hn1 = fminf(fmaxf(accn.y + bb1, 0.f), 1.f);

    float partial = hs0 * W_out[j]         + hs1 * W_out[j + 1]
                  + hn0 * W_out[FTOUT + j] + hn1 * W_out[FTOUT + j + 1];

    #pragma unroll
    for (int off = 32; off > 0; off >>= 1)
        partial += __shfl_down(partial, off);

    if ((tid & 63) == 0) s_red[tid >> 6] = partial;
    __syncthreads();

    if (tid == 0) {
        const float tot = s_red[0] + s_red[1] + s_red[2] + s_red[3] + b_out[0];
        out[b] = 1.0f / (1.0f + expf(-tot));
    }
}

extern "C" void kernel_launch(void* const* d_in, const int* in_sizes, int n_in,
                              void* d_out, int out_size, void* d_ws, size_t ws_size,
                              hipStream_t stream) {
    const int*   stm_idx  = (const int*)d_in[0];
    const int*   nstm_idx = (const int*)d_in[1];
    const float* values   = (const float*)d_in[2];
    const float* W_ft     = (const float*)d_in[4];
    const float* b_ft     = (const float*)d_in[5];
    const float* W_fft    = (const float*)d_in[6];
    const float* b_fft    = (const float*)d_in[7];
    const float* W_out    = (const float*)d_in[8];
    const float* b_out    = (const float*)d_in[9];
    float* out = (float*)d_out;

    const int nnz   = in_sizes[0] / 2;
    const int batch = out_size;

    const size_t wsum_bytes = (size_t)FTIN * FTOUT * sizeof(unsigned short);
    if (ws_size >= wsum_bytes) {
        unsigned short* Wsum = (unsigned short*)d_ws;
        build_wsum<<<(FTIN * FTOUT / 4) / 256, 256, 0, stream>>>(W_ft, W_fft, Wsum);
        nnhalfka_gather<<<batch, 256, 0, stream>>>(
            stm_idx, nstm_idx, values, Wsum, b_ft, b_fft, W_out, b_out, out, nnz);
    } else {
        nnhalfka_fused<<<batch, 256, 0, stream>>>(
            stm_idx, nstm_idx, values, W_ft, b_ft, W_fft, b_fft, W_out, b_out,
            out, nnz);
    }
}

// Round 5
// 83.828 us; speedup vs baseline: 2.0123x; 1.1809x over previous
//
#include <hip/hip_runtime.h>
#include <math.h>

#define MAXF   32
#define FTOUT  512
#define VFT    768
#define FTIN   49152
#define NCHUNK 8
#define CCOLS  64              // columns per chunk (128 B of bf16 = 1 L2 line)
#define RPB    32              // batch rows per block (4 waves x 8 rows)

// ---------------------------------------------------------------------------
// Kernel 1: Wsum[f][j] = bf16_rne( W_ft[f][j] + W_fft[f % 768][j] )
// ---------------------------------------------------------------------------
__global__ __launch_bounds__(256)
void build_wsum(const float* __restrict__ W_ft,
                const float* __restrict__ W_fft,
                unsigned short* __restrict__ Wsum)
{
    const long long e = ((long long)blockIdx.x * blockDim.x + threadIdx.x) * 4;
    const int f = (int)(e >> 9);
    const int j = (int)(e & 511);
    const float4 a = *(const float4*)(W_ft + e);
    const float4 c = *(const float4*)(W_fft + (long long)(f % VFT) * FTOUT + j);
    const float s[4] = {a.x + c.x, a.y + c.y, a.z + c.z, a.w + c.w};
    ushort4 o;
    unsigned short* op = (unsigned short*)&o;
    #pragma unroll
    for (int t = 0; t < 4; ++t) {
        unsigned int u = __float_as_uint(s[t]);
        u += 0x7FFFu + ((u >> 16) & 1u);
        op[t] = (unsigned short)(u >> 16);
    }
    *(ushort4*)(Wsum + e) = o;
}

// ---------------------------------------------------------------------------
// Kernel 1b: pack per-row feature offsets (int32, premultiplied) and values.
// off32[b*64 + k]: k<32 -> stm feature k, k>=32 -> nstm feature k-32.
// val32[b*32 + kk]: shared by both perspectives.
// ---------------------------------------------------------------------------
__global__ __launch_bounds__(256)
void prep_idx(const int* __restrict__ stm_idx,
              const int* __restrict__ nstm_idx,
              const float* __restrict__ values,
              int* __restrict__ off32,
              float* __restrict__ val32,
              int nnz, int batch)
{
    const int t = blockIdx.x * 256 + threadIdx.x;
    if (t >= batch * 64) return;
    const int b = t >> 6;
    const int k = t & 63;
    const int g = b * MAXF + (k & 31);
    const int f = (k < 32 ? stm_idx : nstm_idx)[nnz + g];
    off32[t] = f * FTOUT;
    if (k < 32) val32[b * 32 + k] = values[g];
}

// ---------------------------------------------------------------------------
// Kernel 2: chunked gather. Block = (chunk c = blockIdx&7 -> XCD c, 32 rows).
// Wave handles 8 rows; per row: 8 load-instrs, each = 8 features x 128B
// segment of chunk c. Butterfly-reduce across feature-subgroups, then
// clip+dot -> per-(row,chunk) partial scalar.
// ---------------------------------------------------------------------------
#define CONS(A, W, V) do {                                        \
    A[0] = fmaf(V, __uint_as_float((W).x << 16),         A[0]);   \
    A[1] = fmaf(V, __uint_as_float((W).x & 0xFFFF0000u), A[1]);   \
    A[2] = fmaf(V, __uint_as_float((W).y << 16),         A[2]);   \
    A[3] = fmaf(V, __uint_as_float((W).y & 0xFFFF0000u), A[3]);   \
    A[4] = fmaf(V, __uint_as_float((W).z << 16),         A[4]);   \
    A[5] = fmaf(V, __uint_as_float((W).z & 0xFFFF0000u), A[5]);   \
    A[6] = fmaf(V, __uint_as_float((W).w << 16),         A[6]);   \
    A[7] = fmaf(V, __uint_as_float((W).w & 0xFFFF0000u), A[7]);   \
} while (0)

__global__ __launch_bounds__(256, 4)
void gather_chunk(const unsigned short* __restrict__ Wsum,
                  const int* __restrict__ off32,
                  const float* __restrict__ val32,
                  const float* __restrict__ b_ft,
                  const float* __restrict__ b_fft,
                  const float* __restrict__ W_out,
                  float* __restrict__ partial,
                  int batch)
{
    const int c    = blockIdx.x & (NCHUNK - 1);   // chunk -> XCD (round-robin)
    const int rg   = blockIdx.x >> 3;
    const int tid  = threadIdx.x;
    const int wid  = tid >> 6;
    const int lane = tid & 63;
    const int lg   = lane >> 3;    // feature-subgroup 0..7
    const int cg   = lane & 7;     // colgroup 0..7
    const int col0 = c * CCOLS + cg * 8;

    // hoisted per-lane constants (8 columns owned by this lane)
    float bb[8], wos[8], won[8];
    {
        const float4 a0 = *(const float4*)(b_ft + col0);
        const float4 a1 = *(const float4*)(b_ft + col0 + 4);
        const float4 f0 = *(const float4*)(b_fft + col0);
        const float4 f1 = *(const float4*)(b_fft + col0 + 4);
        bb[0]=a0.x+f0.x; bb[1]=a0.y+f0.y; bb[2]=a0.z+f0.z; bb[3]=a0.w+f0.w;
        bb[4]=a1.x+f1.x; bb[5]=a1.y+f1.y; bb[6]=a1.z+f1.z; bb[7]=a1.w+f1.w;
        const float4 s0 = *(const float4*)(W_out + col0);
        const float4 s1 = *(const float4*)(W_out + col0 + 4);
        const float4 n0 = *(const float4*)(W_out + FTOUT + col0);
        const float4 n1 = *(const float4*)(W_out + FTOUT + col0 + 4);
        wos[0]=s0.x; wos[1]=s0.y; wos[2]=s0.z; wos[3]=s0.w;
        wos[4]=s1.x; wos[5]=s1.y; wos[6]=s1.z; wos[7]=s1.w;
        won[0]=n0.x; won[1]=n0.y; won[2]=n0.z; won[3]=n0.w;
        won[4]=n1.x; won[5]=n1.y; won[6]=n1.z; won[7]=n1.w;
    }
    const unsigned short* base = Wsum + col0;
    const int row0 = rg * RPB + wid * 8;

    for (int r = 0; r < 8; ++r) {
        const int row = row0 + r;
        if (row >= batch) break;

        const int   off_all = off32[row * 64 + lane];
        const float v_all   = val32[row * 32 + (lane & 31)];

        const int o0 = __shfl(off_all,      lg);
        const int o1 = __shfl(off_all,  8 + lg);
        const int o2 = __shfl(off_all, 16 + lg);
        const int o3 = __shfl(off_all, 24 + lg);
        const int o4 = __shfl(off_all, 32 + lg);
        const int o5 = __shfl(off_all, 40 + lg);
        const int o6 = __shfl(off_all, 48 + lg);
        const int o7 = __shfl(off_all, 56 + lg);

        const uint4 w0 = *(const uint4*)(base + o0);
        const uint4 w1 = *(const uint4*)(base + o1);
        const uint4 w2 = *(const uint4*)(base + o2);
        const uint4 w3 = *(const uint4*)(base + o3);
        const uint4 w4 = *(const uint4*)(base + o4);
        const uint4 w5 = *(const uint4*)(base + o5);
        const uint4 w6 = *(const uint4*)(base + o6);
        const uint4 w7 = *(const uint4*)(base + o7);
        __builtin_amdgcn_sched_barrier(0);   // keep 8 gathers in flight

        const float v0 = __shfl(v_all,      lg);   // shared by g=0 and g=4
        const float v1 = __shfl(v_all,  8 + lg);
        const float v2 = __shfl(v_all, 16 + lg);
        const float v3 = __shfl(v_all, 24 + lg);

        float acc_s[8] = {0.f,0.f,0.f,0.f,0.f,0.f,0.f,0.f};
        float acc_n[8] = {0.f,0.f,0.f,0.f,0.f,0.f,0.f,0.f};
        CONS(acc_s, w0, v0); CONS(acc_s, w1, v1);
        CONS(acc_s, w2, v2); CONS(acc_s, w3, v3);
        CONS(acc_n, w4, v0); CONS(acc_n, w5, v1);
        CONS(acc_n, w6, v2); CONS(acc_n, w7, v3);

        // reduce across the 8 feature-subgroups (lane bits 3..5)
        #pragma unroll
        for (int t = 0; t < 8; ++t) {
            acc_s[t] += __shfl_xor(acc_s[t], 8);
            acc_n[t] += __shfl_xor(acc_n[t], 8);
        }
        #pragma unroll
        for (int t = 0; t < 8; ++t) {
            acc_s[t] += __shfl_xor(acc_s[t], 16);
            acc_n[t] += __shfl_xor(acc_n[t], 16);
        }
        #pragma unroll
        for (int t = 0; t < 8; ++t) {
            acc_s[t] += __shfl_xor(acc_s[t], 32);
            acc_n[t] += __shfl_xor(acc_n[t], 32);
        }

        float part = 0.f;
        #pragma unroll
        for (int t = 0; t < 8; ++t) {
            const float hs = fminf(fmaxf(acc_s[t] + bb[t], 0.f), 1.f);
            part = fmaf(hs, wos[t], part);
        }
        #pragma unroll
        for (int t = 0; t < 8; ++t) {
            const float hn = fminf(fmaxf(acc_n[t] + bb[t], 0.f), 1.f);
            part = fmaf(hn, won[t], part);
        }
        // sum the 8 distinct colgroups (lane bits 0..2)
        part += __shfl_xor(part, 1);
        part += __shfl_xor(part, 2);
        part += __shfl_xor(part, 4);

        if (lane == 0) partial[row * NCHUNK + c] = part;
    }
}

// ---------------------------------------------------------------------------
// Kernel 3: combine 8 chunk partials -> sigmoid
// ---------------------------------------------------------------------------
__global__ __launch_bounds__(256)
void final_out(const float* __restrict__ partial,
               const float* __restrict__ b_out,
               float* __restrict__ out, int batch)
{
    const int b = blockIdx.x * 256 + threadIdx.x;
    if (b >= batch) return;
    const float4 p0 = *(const float4*)(partial + b * NCHUNK);
    const float4 p1 = *(const float4*)(partial + b * NCHUNK + 4);
    const float tot = ((p0.x + p0.y) + (p0.z + p0.w))
                    + ((p1.x + p1.y) + (p1.z + p1.w)) + b_out[0];
    out[b] = 1.0f / (1.0f + expf(-tot));
}

// ---------------------------------------------------------------------------
// Fallback A (round-4): monolithic gather, needs only the table in ws.
// ---------------------------------------------------------------------------
__global__ __launch_bounds__(128, 8)
void nnhalfka_gather(const int* __restrict__ stm_idx,
                     const int* __restrict__ nstm_idx,
                     const float* __restrict__ values,
                     const unsigned short* __restrict__ Wsum,
                     const float* __restrict__ b_ft,
                     const float* __restrict__ b_fft,
                     const float* __restrict__ W_out,
                     const float* __restrict__ b_out,
                     float* __restrict__ out,
                     int nnz)
{
    const int b    = blockIdx.x;
    const int tid  = threadIdx.x;
    const int wave = tid >> 6;
    const int lane = tid & 63;

    __shared__ int   s_off[2][MAXF];
    __shared__ float s_v[MAXF];
    __shared__ float s_red[2];

    if (lane < MAXF) {
        const int g = b * MAXF + lane;
        const int* src = wave ? nstm_idx : stm_idx;
        s_off[wave][lane] = src[nnz + g] * FTOUT;
    } else if (wave == 0) {
        s_v[lane - MAXF] = values[b * MAXF + (lane - MAXF)];
    }
    __syncthreads();

    const int jbase = lane * 8;
    float acc[8] = {0.f,0.f,0.f,0.f,0.f,0.f,0.f,0.f};

    #pragma unroll
    for (int g8 = 0; g8 < MAXF / 8; ++g8) {
        uint4 q0 = *(const uint4*)(Wsum + s_off[wave][g8*8+0] + jbase);
        uint4 q1 = *(const uint4*)(Wsum + s_off[wave][g8*8+1] + jbase);
        uint4 q2 = *(const uint4*)(Wsum + s_off[wave][g8*8+2] + jbase);
        uint4 q3 = *(const uint4*)(Wsum + s_off[wave][g8*8+3] + jbase);
        uint4 q4 = *(const uint4*)(Wsum + s_off[wave][g8*8+4] + jbase);
        uint4 q5 = *(const uint4*)(Wsum + s_off[wave][g8*8+5] + jbase);
        uint4 q6 = *(const uint4*)(Wsum + s_off[wave][g8*8+6] + jbase);
        uint4 q7 = *(const uint4*)(Wsum + s_off[wave][g8*8+7] + jbase);
        __builtin_amdgcn_sched_barrier(0);
        CONS(acc, q0, s_v[g8*8+0]); CONS(acc, q1, s_v[g8*8+1]);
        CONS(acc, q2, s_v[g8*8+2]); CONS(acc, q3, s_v[g8*8+3]);
        CONS(acc, q4, s_v[g8*8+4]); CONS(acc, q5, s_v[g8*8+5]);
        CONS(acc, q6, s_v[g8*8+6]); CONS(acc, q7, s_v[g8*8+7]);
    }

    float bb[8], wo[8];
    *(float4*)&bb[0] = *(const float4*)(b_ft + jbase);
    *(float4*)&bb[4] = *(const float4*)(b_ft + jbase + 4);
    {
        const float4 v0 = *(const float4*)(b_fft + jbase);
        const float4 v1 = *(const float4*)(b_fft + jbase + 4);
        bb[0]+=v0.x; bb[1]+=v0.y; bb[2]+=v0.z; bb[3]+=v0.w;
        bb[4]+=v1.x; bb[5]+=v1.y; bb[6]+=v1.z; bb[7]+=v1.w;
    }
    *(float4*)&wo[0] = *(const float4*)(W_out + wave * FTOUT + jbase);
    *(float4*)&wo[4] = *(const float4*)(W_out + wave * FTOUT + jbase + 4);

    float partial = 0.f;
    #pragma unroll
    for (int t = 0; t < 8; ++t) {
        const float h = fminf(fmaxf(acc[t] + bb[t], 0.f), 1.f);
        partial = fmaf(h, wo[t], partial);
    }
    #pragma unroll
    for (int off = 32; off > 0; off >>= 1)
        partial += __shfl_down(partial, off);
    if (lane == 0) s_red[wave] = partial;
    __syncthreads();
    if (tid == 0) {
        const float tot = s_red[0] + s_red[1] + b_out[0];
        out[b] = 1.0f / (1.0f + expf(-tot));
    }
}

// ---------------------------------------------------------------------------
// Fallback B (round-1): no workspace needed.
// ---------------------------------------------------------------------------
__global__ __launch_bounds__(256)
void nnhalfka_fused(const int* __restrict__ stm_idx,
                    const int* __restrict__ nstm_idx,
                    const float* __restrict__ values,
                    const float* __restrict__ W_ft,
                    const float* __restrict__ b_ft,
                    const float* __restrict__ W_fft,
                    const float* __restrict__ b_fft,
                    const float* __restrict__ W_out,
                    const float* __restrict__ b_out,
                    float* __restrict__ out,
                    int nnz)
{
    const int b   = blockIdx.x;
    const int tid = threadIdx.x;

    __shared__ int   s_fs[MAXF], s_fsm[MAXF], s_fn[MAXF], s_fnm[MAXF];
    __shared__ float s_v[MAXF];
    __shared__ float s_red[4];

    if (tid < MAXF) {
        const int g  = b * MAXF + tid;
        const int fs = stm_idx[nnz + g];
        const int fn = nstm_idx[nnz + g];
        s_fs[tid]  = fs * FTOUT;
        s_fsm[tid] = (fs % VFT) * FTOUT;
        s_fn[tid]  = fn * FTOUT;
        s_fnm[tid] = (fn % VFT) * FTOUT;
        s_v[tid]   = values[g];
    }
    __syncthreads();

    const int j = tid * 2;
    float2 accs = make_float2(0.f, 0.f);
    float2 accn = make_float2(0.f, 0.f);

    #pragma unroll 4
    for (int k = 0; k < MAXF; ++k) {
        const float v    = s_v[k];
        const float2 ws  = *(const float2*)(W_ft  + s_fs[k]  + j);
        const float2 wfs = *(const float2*)(W_fft + s_fsm[k] + j);
        const float2 wn  = *(const float2*)(W_ft  + s_fn[k]  + j);
        const float2 wfn = *(const float2*)(W_fft + s_fnm[k] + j);
        accs.x += v * (ws.x + wfs.x);
        accs.y += v * (ws.y + wfs.y);
        accn.x += v * (wn.x + wfn.x);
        accn.y += v * (wn.y + wfn.y);
    }

    const float bb0 = b_ft[j]     + b_fft[j];
    const float bb1 = b_ft[j + 1] + b_fft[j + 1];
    const float hs0 = fminf(fmaxf(accs.x + bb0, 0.f), 1.f);
    const float hs1 = fminf(fmaxf(accs.y + bb1, 0.f), 1.f);
    const float hn0 = fminf(fmaxf(accn.x + bb0, 0.f), 1.f);
    const float hn1 = fminf(fmaxf(accn.y + bb1, 0.f), 1.f);

    float partial = hs0 * W_out[j]         + hs1 * W_out[j + 1]
                  + hn0 * W_out[FTOUT + j] + hn1 * W_out[FTOUT + j + 1];
    #pragma unroll
    for (int off = 32; off > 0; off >>= 1)
        partial += __shfl_down(partial, off);
    if ((tid & 63) == 0) s_red[tid >> 6] = partial;
    __syncthreads();
    if (tid == 0) {
        const float tot = s_red[0] + s_red[1] + s_red[2] + s_red[3] + b_out[0];
        out[b] = 1.0f / (1.0f + expf(-tot));
    }
}

extern "C" void kernel_launch(void* const* d_in, const int* in_sizes, int n_in,
                              void* d_out, int out_size, void* d_ws, size_t ws_size,
                              hipStream_t stream) {
    const int*   stm_idx  = (const int*)d_in[0];
    const int*   nstm_idx = (const int*)d_in[1];
    const float* values   = (const float*)d_in[2];
    const float* W_ft     = (const float*)d_in[4];
    const float* b_ft     = (const float*)d_in[5];
    const float* W_fft    = (const float*)d_in[6];
    const float* b_fft    = (const float*)d_in[7];
    const float* W_out    = (const float*)d_in[8];
    const float* b_out    = (const float*)d_in[9];
    float* out = (float*)d_out;

    const int nnz   = in_sizes[0] / 2;
    const int batch = out_size;

    const size_t WSUM_B = (size_t)FTIN * FTOUT * 2;          // 50,331,648
    const size_t OFF_B  = (size_t)batch * 64 * 4;
    const size_t VAL_B  = (size_t)batch * 32 * 4;
    const size_t PART_B = (size_t)batch * NCHUNK * 4;
    const size_t need_chunked = WSUM_B + OFF_B + VAL_B + PART_B;

    if (ws_size >= need_chunked) {
        unsigned short* Wsum = (unsigned short*)d_ws;
        int*   off32   = (int*)((char*)d_ws + WSUM_B);
        float* val32   = (float*)((char*)d_ws + WSUM_B + OFF_B);
        float* partial = (float*)((char*)d_ws + WSUM_B + OFF_B + VAL_B);

        build_wsum<<<(FTIN * FTOUT / 4) / 256, 256, 0, stream>>>(W_ft, W_fft, Wsum);
        prep_idx<<<(batch * 64 + 255) / 256, 256, 0, stream>>>(
            stm_idx, nstm_idx, values, off32, val32, nnz, batch);
        gather_chunk<<<((batch + RPB - 1) / RPB) * NCHUNK, 256, 0, stream>>>(
            Wsum, off32, val32, b_ft, b_fft, W_out, partial, batch);
        final_out<<<(batch + 255) / 256, 256, 0, stream>>>(partial, b_out, out, batch);
    } else if (ws_size >= WSUM_B) {
        unsigned short* Wsum = (unsigned short*)d_ws;
        build_wsum<<<(FTIN * FTOUT / 4) / 256, 256, 0, stream>>>(W_ft, W_fft, Wsum);
        nnhalfka_gather<<<batch, 128, 0, stream>>>(
            stm_idx, nstm_idx, values, Wsum, b_ft, b_fft, W_out, b_out, out, nnz);
    } else {
        nnhalfka_fused<<<batch, 256, 0, stream>>>(
            stm_idx, nstm_idx, values, W_ft, b_ft, W_fft, b_fft, W_out, b_out,
            out, nnz);
    }
}

// Round 6
// 80.002 us; speedup vs baseline: 2.1086x; 1.0478x over previous
//
#include <hip/hip_runtime.h>
#include <math.h>

#define MAXF   32
#define FTOUT  512
#define VFT    768
#define FTIN   49152
#define NCHUNK 8
#define RPB    32              // batch rows per block (4 waves x 4 iters x 2 rows)

// ---------------------------------------------------------------------------
// Kernel 1: Wsum[f][j] = bf16_rne( W_ft[f][j] + W_fft[f % 768][j] )
// ---------------------------------------------------------------------------
__global__ __launch_bounds__(256)
void build_wsum(const float* __restrict__ W_ft,
                const float* __restrict__ W_fft,
                unsigned short* __restrict__ Wsum)
{
    const long long e = ((long long)blockIdx.x * blockDim.x + threadIdx.x) * 4;
    const int f = (int)(e >> 9);
    const int j = (int)(e & 511);
    const float4 a = *(const float4*)(W_ft + e);
    const float4 c = *(const float4*)(W_fft + (long long)(f % VFT) * FTOUT + j);
    const float s[4] = {a.x + c.x, a.y + c.y, a.z + c.z, a.w + c.w};
    ushort4 o;
    unsigned short* op = (unsigned short*)&o;
    #pragma unroll
    for (int t = 0; t < 4; ++t) {
        unsigned int u = __float_as_uint(s[t]);
        u += 0x7FFFu + ((u >> 16) & 1u);
        op[t] = (unsigned short)(u >> 16);
    }
    *(ushort4*)(Wsum + e) = o;
}

// ---------------------------------------------------------------------------
// Kernel 1b: pack per-row feature BYTE offsets (f*1024) and values.
// off32[b*64 + k]: k<32 stm, k>=32 nstm. val32[b*32 + kk].
// ---------------------------------------------------------------------------
__global__ __launch_bounds__(256)
void prep_idx(const int* __restrict__ stm_idx,
              const int* __restrict__ nstm_idx,
              const float* __restrict__ values,
              int* __restrict__ off32,
              float* __restrict__ val32,
              int nnz, int batch)
{
    const int t = blockIdx.x * 256 + threadIdx.x;
    if (t >= batch * 64) return;
    const int b = t >> 6;
    const int k = t & 63;
    const int g = b * MAXF + (k & 31);
    const int f = (k < 32 ? stm_idx : nstm_idx)[nnz + g];
    off32[t] = f * (FTOUT * 2);          // byte offset into bf16 table
    if (k < 32) val32[b * 32 + k] = values[g];
}

#define CONS(A, W, V) do {                                        \
    A[0] = fmaf(V, __uint_as_float((W).x << 16),         A[0]);   \
    A[1] = fmaf(V, __uint_as_float((W).x & 0xFFFF0000u), A[1]);   \
    A[2] = fmaf(V, __uint_as_float((W).y << 16),         A[2]);   \
    A[3] = fmaf(V, __uint_as_float((W).y & 0xFFFF0000u), A[3]);   \
    A[4] = fmaf(V, __uint_as_float((W).z << 16),         A[4]);   \
    A[5] = fmaf(V, __uint_as_float((W).z & 0xFFFF0000u), A[5]);   \
    A[6] = fmaf(V, __uint_as_float((W).w << 16),         A[6]);   \
    A[7] = fmaf(V, __uint_as_float((W).w & 0xFFFF0000u), A[7]);   \
} while (0)

// ---------------------------------------------------------------------------
// Kernel 2: chunked gather, 2 rows per wave-iteration.
// lane = (r:1)(fg:2)(cg:3). Per iter: 16 gathers (8 stm + 8 nstm) covering
// 2 rows x 64 feats x 64 cols. fg-butterfly = 2 stages; epilogue shared by
// 2 rows. Offsets/values staged in LDS per block.
// ---------------------------------------------------------------------------
__global__ __launch_bounds__(256, 4)
void gather_chunk2(const unsigned short* __restrict__ Wsum,
                   const int* __restrict__ off32,
                   const float* __restrict__ val32,
                   const float* __restrict__ b_ft,
                   const float* __restrict__ b_fft,
                   const float* __restrict__ W_out,
                   float* __restrict__ partial,
                   int batch)
{
    const int c    = blockIdx.x & (NCHUNK - 1);   // chunk -> XCD (round-robin)
    const int rg   = blockIdx.x >> 3;
    const int tid  = threadIdx.x;
    const int wid  = tid >> 6;
    const int lane = tid & 63;
    const int r    = lane >> 5;        // row within pair
    const int fg   = (lane >> 3) & 3;  // feature group (4)
    const int cg   = lane & 7;         // col octet (8)

    __shared__ int   s_off[RPB][64];
    __shared__ float s_val[RPB][32];

    const int row_base = rg * RPB;

    // stage offsets + values (coalesced)
    #pragma unroll
    for (int i = 0; i < 8; ++i) {
        const int idx = i * 256 + tid;                 // RPB*64 = 2048
        const int gsrc = row_base * 64 + idx;
        ((int*)s_off)[idx] = (gsrc < batch * 64) ? off32[gsrc] : 0;
    }
    #pragma unroll
    for (int i = 0; i < 4; ++i) {
        const int idx = i * 256 + tid;                 // RPB*32 = 1024
        const int gsrc = row_base * 32 + idx;
        ((float*)s_val)[idx] = (gsrc < batch * 32) ? val32[gsrc] : 0.f;
    }
    __syncthreads();

    // per-lane constants: 8 cols c*64 + cg*8 .. +8
    const int col = c * 64 + cg * 8;
    float bbq[8], wos[8], won[8];
    {
        const float4 a0 = *(const float4*)(b_ft + col);
        const float4 a1 = *(const float4*)(b_ft + col + 4);
        const float4 f0 = *(const float4*)(b_fft + col);
        const float4 f1 = *(const float4*)(b_fft + col + 4);
        bbq[0]=(a0.x+f0.x)*0.25f; bbq[1]=(a0.y+f0.y)*0.25f;
        bbq[2]=(a0.z+f0.z)*0.25f; bbq[3]=(a0.w+f0.w)*0.25f;
        bbq[4]=(a1.x+f1.x)*0.25f; bbq[5]=(a1.y+f1.y)*0.25f;
        bbq[6]=(a1.z+f1.z)*0.25f; bbq[7]=(a1.w+f1.w)*0.25f;
        const float4 s0 = *(const float4*)(W_out + col);
        const float4 s1 = *(const float4*)(W_out + col + 4);
        const float4 n0 = *(const float4*)(W_out + FTOUT + col);
        const float4 n1 = *(const float4*)(W_out + FTOUT + col + 4);
        wos[0]=s0.x; wos[1]=s0.y; wos[2]=s0.z; wos[3]=s0.w;
        wos[4]=s1.x; wos[5]=s1.y; wos[6]=s1.z; wos[7]=s1.w;
        won[0]=n0.x; won[1]=n0.y; won[2]=n0.z; won[3]=n0.w;
        won[4]=n1.x; won[5]=n1.y; won[6]=n1.z; won[7]=n1.w;
    }

    const char* wb = (const char*)Wsum;
    const unsigned colb = (unsigned)(c * 128 + cg * 16);  // byte offset in row

    #pragma unroll
    for (int it = 0; it < 4; ++it) {
        const int lrow  = wid * 8 + 2 * it + r;           // 0..31
        const int row_g = row_base + lrow;

        const int*   po = &s_off[lrow][fg];
        const float* pv = &s_val[lrow][fg];

        // all LDS reads upfront
        const int o0 = po[0],  o1 = po[4],  o2 = po[8],  o3 = po[12];
        const int o4 = po[16], o5 = po[20], o6 = po[24], o7 = po[28];
        const int q0 = po[32], q1 = po[36], q2 = po[40], q3 = po[44];
        const int q4 = po[48], q5 = po[52], q6 = po[56], q7 = po[60];
        const float v0 = pv[0],  v1 = pv[4],  v2 = pv[8],  v3 = pv[12];
        const float v4 = pv[16], v5 = pv[20], v6 = pv[24], v7 = pv[28];

        // stm gathers (8 x 1KB)
        const uint4 a0 = *(const uint4*)(wb + (unsigned)o0 + colb);
        const uint4 a1 = *(const uint4*)(wb + (unsigned)o1 + colb);
        const uint4 a2 = *(const uint4*)(wb + (unsigned)o2 + colb);
        const uint4 a3 = *(const uint4*)(wb + (unsigned)o3 + colb);
        const uint4 a4 = *(const uint4*)(wb + (unsigned)o4 + colb);
        const uint4 a5 = *(const uint4*)(wb + (unsigned)o5 + colb);
        const uint4 a6 = *(const uint4*)(wb + (unsigned)o6 + colb);
        const uint4 a7 = *(const uint4*)(wb + (unsigned)o7 + colb);
        __builtin_amdgcn_sched_barrier(0);

        float acc_s[8], acc_n[8];
        #pragma unroll
        for (int t = 0; t < 8; ++t) { acc_s[t] = bbq[t]; acc_n[t] = bbq[t]; }

        CONS(acc_s, a0, v0); CONS(acc_s, a1, v1);
        CONS(acc_s, a2, v2); CONS(acc_s, a3, v3);
        CONS(acc_s, a4, v4); CONS(acc_s, a5, v5);
        CONS(acc_s, a6, v6); CONS(acc_s, a7, v7);

        // nstm gathers (reuse values)
        const uint4 b0 = *(const uint4*)(wb + (unsigned)q0 + colb);
        const uint4 b1 = *(const uint4*)(wb + (unsigned)q1 + colb);
        const uint4 b2 = *(const uint4*)(wb + (unsigned)q2 + colb);
        const uint4 b3 = *(const uint4*)(wb + (unsigned)q3 + colb);
        const uint4 b4 = *(const uint4*)(wb + (unsigned)q4 + colb);
        const uint4 b5 = *(const uint4*)(wb + (unsigned)q5 + colb);
        const uint4 b6 = *(const uint4*)(wb + (unsigned)q6 + colb);
        const uint4 b7 = *(const uint4*)(wb + (unsigned)q7 + colb);
        __builtin_amdgcn_sched_barrier(0);

        CONS(acc_n, b0, v0); CONS(acc_n, b1, v1);
        CONS(acc_n, b2, v2); CONS(acc_n, b3, v3);
        CONS(acc_n, b4, v4); CONS(acc_n, b5, v5);
        CONS(acc_n, b6, v6); CONS(acc_n, b7, v7);

        // fg-butterfly: 2 stages (lane bits 3,4)
        #pragma unroll
        for (int t = 0; t < 8; ++t) {
            acc_s[t] += __shfl_xor(acc_s[t], 8);
            acc_n[t] += __shfl_xor(acc_n[t], 8);
        }
        #pragma unroll
        for (int t = 0; t < 8; ++t) {
            acc_s[t] += __shfl_xor(acc_s[t], 16);
            acc_n[t] += __shfl_xor(acc_n[t], 16);
        }

        // clip + dot (bias already inside acc)
        float part = 0.f;
        #pragma unroll
        for (int t = 0; t < 8; ++t) {
            const float hs = fminf(fmaxf(acc_s[t], 0.f), 1.f);
            part = fmaf(hs, wos[t], part);
        }
        #pragma unroll
        for (int t = 0; t < 8; ++t) {
            const float hn = fminf(fmaxf(acc_n[t], 0.f), 1.f);
            part = fmaf(hn, won[t], part);
        }
        // cg-sum (lane bits 0..2)
        part += __shfl_xor(part, 1);
        part += __shfl_xor(part, 2);
        part += __shfl_xor(part, 4);

        if ((lane & 31) == 0 && row_g < batch)
            partial[row_g * NCHUNK + c] = part;
    }
}

// ---------------------------------------------------------------------------
// Kernel 3: combine 8 chunk partials -> sigmoid
// ---------------------------------------------------------------------------
__global__ __launch_bounds__(256)
void final_out(const float* __restrict__ partial,
               const float* __restrict__ b_out,
               float* __restrict__ out, int batch)
{
    const int b = blockIdx.x * 256 + threadIdx.x;
    if (b >= batch) return;
    const float4 p0 = *(const float4*)(partial + b * NCHUNK);
    const float4 p1 = *(const float4*)(partial + b * NCHUNK + 4);
    const float tot = ((p0.x + p0.y) + (p0.z + p0.w))
                    + ((p1.x + p1.y) + (p1.z + p1.w)) + b_out[0];
    out[b] = 1.0f / (1.0f + expf(-tot));
}

// ---------------------------------------------------------------------------
// Fallback A: monolithic gather (needs only the table in ws).
// ---------------------------------------------------------------------------
__global__ __launch_bounds__(128, 8)
void nnhalfka_gather(const int* __restrict__ stm_idx,
                     const int* __restrict__ nstm_idx,
                     const float* __restrict__ values,
                     const unsigned short* __restrict__ Wsum,
                     const float* __restrict__ b_ft,
                     const float* __restrict__ b_fft,
                     const float* __restrict__ W_out,
                     const float* __restrict__ b_out,
                     float* __restrict__ out,
                     int nnz)
{
    const int b    = blockIdx.x;
    const int tid  = threadIdx.x;
    const int wave = tid >> 6;
    const int lane = tid & 63;

    __shared__ int   s_off[2][MAXF];
    __shared__ float s_v[MAXF];
    __shared__ float s_red[2];

    if (lane < MAXF) {
        const int g = b * MAXF + lane;
        const int* src = wave ? nstm_idx : stm_idx;
        s_off[wave][lane] = src[nnz + g] * FTOUT;
    } else if (wave == 0) {
        s_v[lane - MAXF] = values[b * MAXF + (lane - MAXF)];
    }
    __syncthreads();

    const int jbase = lane * 8;
    float acc[8] = {0.f,0.f,0.f,0.f,0.f,0.f,0.f,0.f};

    #pragma unroll
    for (int g8 = 0; g8 < MAXF / 8; ++g8) {
        uint4 q0 = *(const uint4*)(Wsum + s_off[wave][g8*8+0] + jbase);
        uint4 q1 = *(const uint4*)(Wsum + s_off[wave][g8*8+1] + jbase);
        uint4 q2 = *(const uint4*)(Wsum + s_off[wave][g8*8+2] + jbase);
        uint4 q3 = *(const uint4*)(Wsum + s_off[wave][g8*8+3] + jbase);
        uint4 q4 = *(const uint4*)(Wsum + s_off[wave][g8*8+4] + jbase);
        uint4 q5 = *(const uint4*)(Wsum + s_off[wave][g8*8+5] + jbase);
        uint4 q6 = *(const uint4*)(Wsum + s_off[wave][g8*8+6] + jbase);
        uint4 q7 = *(const uint4*)(Wsum + s_off[wave][g8*8+7] + jbase);
        __builtin_amdgcn_sched_barrier(0);
        CONS(acc, q0, s_v[g8*8+0]); CONS(acc, q1, s_v[g8*8+1]);
        CONS(acc, q2, s_v[g8*8+2]); CONS(acc, q3, s_v[g8*8+3]);
        CONS(acc, q4, s_v[g8*8+4]); CONS(acc, q5, s_v[g8*8+5]);
        CONS(acc, q6, s_v[g8*8+6]); CONS(acc, q7, s_v[g8*8+7]);
    }

    float bb[8], wo[8];
    *(float4*)&bb[0] = *(const float4*)(b_ft + jbase);
    *(float4*)&bb[4] = *(const float4*)(b_ft + jbase + 4);
    {
        const float4 v0 = *(const float4*)(b_fft + jbase);
        const float4 v1 = *(const float4*)(b_fft + jbase + 4);
        bb[0]+=v0.x; bb[1]+=v0.y; bb[2]+=v0.z; bb[3]+=v0.w;
        bb[4]+=v1.x; bb[5]+=v1.y; bb[6]+=v1.z; bb[7]+=v1.w;
    }
    *(float4*)&wo[0] = *(const float4*)(W_out + wave * FTOUT + jbase);
    *(float4*)&wo[4] = *(const float4*)(W_out + wave * FTOUT + jbase + 4);

    float partial = 0.f;
    #pragma unroll
    for (int t = 0; t < 8; ++t) {
        const float h = fminf(fmaxf(acc[t] + bb[t], 0.f), 1.f);
        partial = fmaf(h, wo[t], partial);
    }
    #pragma unroll
    for (int off = 32; off > 0; off >>= 1)
        partial += __shfl_down(partial, off);
    if (lane == 0) s_red[wave] = partial;
    __syncthreads();
    if (tid == 0) {
        const float tot = s_red[0] + s_red[1] + b_out[0];
        out[b] = 1.0f / (1.0f + expf(-tot));
    }
}

// ---------------------------------------------------------------------------
// Fallback B: no workspace needed.
// ---------------------------------------------------------------------------
__global__ __launch_bounds__(256)
void nnhalfka_fused(const int* __restrict__ stm_idx,
                    const int* __restrict__ nstm_idx,
                    const float* __restrict__ values,
                    const float* __restrict__ W_ft,
                    const float* __restrict__ b_ft,
                    const float* __restrict__ W_fft,
                    const float* __restrict__ b_fft,
                    const float* __restrict__ W_out,
                    const float* __restrict__ b_out,
                    float* __restrict__ out,
                    int nnz)
{
    const int b   = blockIdx.x;
    const int tid = threadIdx.x;

    __shared__ int   s_fs[MAXF], s_fsm[MAXF], s_fn[MAXF], s_fnm[MAXF];
    __shared__ float s_v[MAXF];
    __shared__ float s_red[4];

    if (tid < MAXF) {
        const int g  = b * MAXF + tid;
        const int fs = stm_idx[nnz + g];
        const int fn = nstm_idx[nnz + g];
        s_fs[tid]  = fs * FTOUT;
        s_fsm[tid] = (fs % VFT) * FTOUT;
        s_fn[tid]  = fn * FTOUT;
        s_fnm[tid] = (fn % VFT) * FTOUT;
        s_v[tid]   = values[g];
    }
    __syncthreads();

    const int j = tid * 2;
    float2 accs = make_float2(0.f, 0.f);
    float2 accn = make_float2(0.f, 0.f);

    #pragma unroll 4
    for (int k = 0; k < MAXF; ++k) {
        const float v    = s_v[k];
        const float2 ws  = *(const float2*)(W_ft  + s_fs[k]  + j);
        const float2 wfs = *(const float2*)(W_fft + s_fsm[k] + j);
        const float2 wn  = *(const float2*)(W_ft  + s_fn[k]  + j);
        const float2 wfn = *(const float2*)(W_fft + s_fnm[k] + j);
        accs.x += v * (ws.x + wfs.x);
        accs.y += v * (ws.y + wfs.y);
        accn.x += v * (wn.x + wfn.x);
        accn.y += v * (wn.y + wfn.y);
    }

    const float bb0 = b_ft[j]     + b_fft[j];
    const float bb1 = b_ft[j + 1] + b_fft[j + 1];
    const float hs0 = fminf(fmaxf(accs.x + bb0, 0.f), 1.f);
    const float hs1 = fminf(fmaxf(accs.y + bb1, 0.f), 1.f);
    const float hn0 = fminf(fmaxf(accn.x + bb0, 0.f), 1.f);
    const float hn1 = fminf(fmaxf(accn.y + bb1, 0.f), 1.f);

    float partial = hs0 * W_out[j]         + hs1 * W_out[j + 1]
                  + hn0 * W_out[FTOUT + j] + hn1 * W_out[FTOUT + j + 1];
    #pragma unroll
    for (int off = 32; off > 0; off >>= 1)
        partial += __shfl_down(partial, off);
    if ((tid & 63) == 0) s_red[tid >> 6] = partial;
    __syncthreads();
    if (tid == 0) {
        const float tot = s_red[0] + s_red[1] + s_red[2] + s_red[3] + b_out[0];
        out[b] = 1.0f / (1.0f + expf(-tot));
    }
}

extern "C" void kernel_launch(void* const* d_in, const int* in_sizes, int n_in,
                              void* d_out, int out_size, void* d_ws, size_t ws_size,
                              hipStream_t stream) {
    const int*   stm_idx  = (const int*)d_in[0];
    const int*   nstm_idx = (const int*)d_in[1];
    const float* values   = (const float*)d_in[2];
    const float* W_ft     = (const float*)d_in[4];
    const float* b_ft     = (const float*)d_in[5];
    const float* W_fft    = (const float*)d_in[6];
    const float* b_fft    = (const float*)d_in[7];
    const float* W_out    = (const float*)d_in[8];
    const float* b_out    = (const float*)d_in[9];
    float* out = (float*)d_out;

    const int nnz   = in_sizes[0] / 2;
    const int batch = out_size;

    const size_t WSUM_B = (size_t)FTIN * FTOUT * 2;
    const size_t OFF_B  = (size_t)batch * 64 * 4;
    const size_t VAL_B  = (size_t)batch * 32 * 4;
    const size_t PART_B = (size_t)batch * NCHUNK * 4;
    const size_t need_chunked = WSUM_B + OFF_B + VAL_B + PART_B;

    if (ws_size >= need_chunked) {
        unsigned short* Wsum = (unsigned short*)d_ws;
        int*   off32   = (int*)((char*)d_ws + WSUM_B);
        float* val32   = (float*)((char*)d_ws + WSUM_B + OFF_B);
        float* partial = (float*)((char*)d_ws + WSUM_B + OFF_B + VAL_B);

        build_wsum<<<(FTIN * FTOUT / 4) / 256, 256, 0, stream>>>(W_ft, W_fft, Wsum);
        prep_idx<<<(batch * 64 + 255) / 256, 256, 0, stream>>>(
            stm_idx, nstm_idx, values, off32, val32, nnz, batch);
        gather_chunk2<<<((batch + RPB - 1) / RPB) * NCHUNK, 256, 0, stream>>>(
            Wsum, off32, val32, b_ft, b_fft, W_out, partial, batch);
        final_out<<<(batch + 255) / 256, 256, 0, stream>>>(partial, b_out, out, batch);
    } else if (ws_size >= WSUM_B) {
        unsigned short* Wsum = (unsigned short*)d_ws;
        build_wsum<<<(FTIN * FTOUT / 4) / 256, 256, 0, stream>>>(W_ft, W_fft, Wsum);
        nnhalfka_gather<<<batch, 128, 0, stream>>>(
            stm_idx, nstm_idx, values, Wsum, b_ft, b_fft, W_out, b_out, out, nnz);
    } else {
        nnhalfka_fused<<<batch, 256, 0, stream>>>(
            stm_idx, nstm_idx, values, W_ft, b_ft, W_fft, b_fft, W_out, b_out,
            out, nnz);
    }
}

// Round 9
// 68.644 us; speedup vs baseline: 2.4575x; 1.1655x over previous
//
#include <hip/hip_runtime.h>
#include <math.h>

#define MAXF   32
#define FTOUT  512
#define VFT    768
#define FTIN   49152
#define NCHUNK 8
#define RPB    32              // batch rows per block (4 waves x 4 iters x 2 rows)

// ---------------------------------------------------------------------------
// Kernel 1: per-feature-row quantize: Wq[f][j] = u8( rint((W_ft+W_fft)/scale_f) + 128 )
// scale_f = rowmax|w| / 127. One wave per feature row.
// ---------------------------------------------------------------------------
__global__ __launch_bounds__(256)
void build_q8(const float* __restrict__ W_ft,
              const float* __restrict__ W_fft,
              unsigned char* __restrict__ Wq,
              float* __restrict__ scale)
{
    const int f    = blockIdx.x * 4 + (threadIdx.x >> 6);
    const int lane = threadIdx.x & 63;
    const long long rb = (long long)f * FTOUT + lane * 8;
    const float4 a0 = *(const float4*)(W_ft + rb);
    const float4 a1 = *(const float4*)(W_ft + rb + 4);
    const int fv = f % VFT;
    const float4 c0 = *(const float4*)(W_fft + fv * FTOUT + lane * 8);
    const float4 c1 = *(const float4*)(W_fft + fv * FTOUT + lane * 8 + 4);
    float w[8] = {a0.x+c0.x, a0.y+c0.y, a0.z+c0.z, a0.w+c0.w,
                  a1.x+c1.x, a1.y+c1.y, a1.z+c1.z, a1.w+c1.w};
    float m = fabsf(w[0]);
    #pragma unroll
    for (int t = 1; t < 8; ++t) m = fmaxf(m, fabsf(w[t]));
    #pragma unroll
    for (int s = 1; s < 64; s <<= 1) m = fmaxf(m, __shfl_xor(m, s));
    const float inv = (m > 0.f) ? 127.f / m : 0.f;
    if (lane == 0) scale[f] = (m > 0.f) ? m * (1.f / 127.f) : 0.f;
    unsigned u[8];
    #pragma unroll
    for (int t = 0; t < 8; ++t)
        u[t] = (unsigned)((int)rintf(w[t] * inv) + 128);
    uint2 o;
    o.x = u[0] | (u[1] << 8) | (u[2] << 16) | (u[3] << 24);
    o.y = u[4] | (u[5] << 8) | (u[6] << 16) | (u[7] << 24);
    *(uint2*)(Wq + (long long)f * FTOUT + lane * 8) = o;
}

// ---------------------------------------------------------------------------
// Kernel 1b: pack per-row feature ids (u16) and pre-scaled values v*scale[f].
// off16[b*64+k]: k<32 stm, k>=32 nstm. val_s/val_n[b*32+kk].
// ---------------------------------------------------------------------------
__global__ __launch_bounds__(256)
void prep_idx(const int* __restrict__ stm_idx,
              const int* __restrict__ nstm_idx,
              const float* __restrict__ values,
              const float* __restrict__ scale,
              unsigned short* __restrict__ off16,
              float* __restrict__ val_s,
              float* __restrict__ val_n,
              int nnz, int batch)
{
    const int t = blockIdx.x * 256 + threadIdx.x;
    if (t >= batch * 64) return;
    const int b = t >> 6;
    const int k = t & 63;
    const int g = b * MAXF + (k & 31);
    const int f = (k < 32 ? stm_idx : nstm_idx)[nnz + g];
    off16[t] = (unsigned short)f;
    const float vs = values[g] * scale[f];
    if (k < 32) val_s[b * 32 + k] = vs;
    else        val_n[b * 32 + (k - 32)] = vs;
}

// biased-u8 consume: A[t] += V * byte_t(W)   (bias handled via corr)
#define CONS_U8(A, W, V) do {                                     \
    A[0] = fmaf(V, (float)((W).x & 0xffu),         A[0]);         \
    A[1] = fmaf(V, (float)(((W).x >> 8)  & 0xffu), A[1]);         \
    A[2] = fmaf(V, (float)(((W).x >> 16) & 0xffu), A[2]);         \
    A[3] = fmaf(V, (float)((W).x >> 24),           A[3]);         \
    A[4] = fmaf(V, (float)((W).y & 0xffu),         A[4]);         \
    A[5] = fmaf(V, (float)(((W).y >> 8)  & 0xffu), A[5]);         \
    A[6] = fmaf(V, (float)(((W).y >> 16) & 0xffu), A[6]);         \
    A[7] = fmaf(V, (float)((W).y >> 24),           A[7]);         \
} while (0)

// ---------------------------------------------------------------------------
// Kernel 2: chunked int8 gather, 2 rows per wave-iteration.
// lane = (r:1)(fg:2)(cg:3). Per iter: 16 uint2 gathers (8 stm + 8 nstm),
// each instr = 8 features x 64 B chunk segment. Chunk c pinned to XCD c.
// ---------------------------------------------------------------------------
__global__ __launch_bounds__(256, 4)
void gather_q8(const unsigned char* __restrict__ Wq,
               const unsigned short* __restrict__ off16,
               const float* __restrict__ val_s,
               const float* __restrict__ val_n,
               const float* __restrict__ b_ft,
               const float* __restrict__ b_fft,
               const float* __restrict__ W_out,
               float* __restrict__ partial,
               int batch)
{
    const int c    = blockIdx.x & (NCHUNK - 1);   // chunk -> XCD
    const int rg   = blockIdx.x >> 3;
    const int tid  = threadIdx.x;
    const int wid  = tid >> 6;
    const int lane = tid & 63;
    const int r    = lane >> 5;
    const int fg   = (lane >> 3) & 3;
    const int cg   = lane & 7;

    __shared__ int   s_off[RPB][64];    // byte offsets f*512
    __shared__ float s_vs[RPB][32];
    __shared__ float s_vn[RPB][32];

    const int row_base = rg * RPB;

    // stage offsets + values (coalesced). 2048 u16 -> 4 u32 per thread.
    {
        const unsigned* src = (const unsigned*)(off16 + row_base * 64); // 1024 u32
        const unsigned p0 = src[tid * 4 + 0];
        const unsigned p1 = src[tid * 4 + 1];
        const unsigned p2 = src[tid * 4 + 2];
        const unsigned p3 = src[tid * 4 + 3];
        int* so = (int*)s_off;
        so[tid * 8 + 0] = (int)(p0 & 0xffffu) << 9;
        so[tid * 8 + 1] = (int)(p0 >> 16)     << 9;
        so[tid * 8 + 2] = (int)(p1 & 0xffffu) << 9;
        so[tid * 8 + 3] = (int)(p1 >> 16)     << 9;
        so[tid * 8 + 4] = (int)(p2 & 0xffffu) << 9;
        so[tid * 8 + 5] = (int)(p2 >> 16)     << 9;
        so[tid * 8 + 6] = (int)(p3 & 0xffffu) << 9;
        so[tid * 8 + 7] = (int)(p3 >> 16)     << 9;
        ((float4*)s_vs)[tid] = ((const float4*)(val_s + row_base * 32))[tid];
        ((float4*)s_vn)[tid] = ((const float4*)(val_n + row_base * 32))[tid];
    }
    __syncthreads();

    // per-lane constants: 8 cols at col = c*64 + cg*8
    const int col = c * 64 + cg * 8;
    float bbq[8], wos[8], won[8];
    {
        const float4 a0 = *(const float4*)(b_ft + col);
        const float4 a1 = *(const float4*)(b_ft + col + 4);
        const float4 f0 = *(const float4*)(b_fft + col);
        const float4 f1 = *(const float4*)(b_fft + col + 4);
        bbq[0]=(a0.x+f0.x)*0.25f; bbq[1]=(a0.y+f0.y)*0.25f;
        bbq[2]=(a0.z+f0.z)*0.25f; bbq[3]=(a0.w+f0.w)*0.25f;
        bbq[4]=(a1.x+f1.x)*0.25f; bbq[5]=(a1.y+f1.y)*0.25f;
        bbq[6]=(a1.z+f1.z)*0.25f; bbq[7]=(a1.w+f1.w)*0.25f;
        const float4 s0 = *(const float4*)(W_out + col);
        const float4 s1 = *(const float4*)(W_out + col + 4);
        const float4 n0 = *(const float4*)(W_out + FTOUT + col);
        const float4 n1 = *(const float4*)(W_out + FTOUT + col + 4);
        wos[0]=s0.x; wos[1]=s0.y; wos[2]=s0.z; wos[3]=s0.w;
        wos[4]=s1.x; wos[5]=s1.y; wos[6]=s1.z; wos[7]=s1.w;
        won[0]=n0.x; won[1]=n0.y; won[2]=n0.z; won[3]=n0.w;
        won[4]=n1.x; won[5]=n1.y; won[6]=n1.z; won[7]=n1.w;
    }

    const char* wb = (const char*)Wq;
    const unsigned colb = (unsigned)(c * 64 + cg * 8);  // byte offset in 512B row

    #pragma unroll
    for (int it = 0; it < 4; ++it) {
        const int lrow  = wid * 8 + 2 * it + r;
        const int row_g = row_base + lrow;

        const int*   po = &s_off[lrow][fg];
        const float* ps = &s_vs[lrow][fg];
        const float* pn = &s_vn[lrow][fg];

        const int o0 = po[0],  o1 = po[4],  o2 = po[8],  o3 = po[12];
        const int o4 = po[16], o5 = po[20], o6 = po[24], o7 = po[28];
        const int q0 = po[32], q1 = po[36], q2 = po[40], q3 = po[44];
        const int q4 = po[48], q5 = po[52], q6 = po[56], q7 = po[60];
        const float vs0 = ps[0],  vs1 = ps[4],  vs2 = ps[8],  vs3 = ps[12];
        const float vs4 = ps[16], vs5 = ps[20], vs6 = ps[24], vs7 = ps[28];
        const float vn0 = pn[0],  vn1 = pn[4],  vn2 = pn[8],  vn3 = pn[12];
        const float vn4 = pn[16], vn5 = pn[20], vn6 = pn[24], vn7 = pn[28];

        // stm gathers (8 x 512B instr)
        const uint2 a0 = *(const uint2*)(wb + (unsigned)o0 + colb);
        const uint2 a1 = *(const uint2*)(wb + (unsigned)o1 + colb);
        const uint2 a2 = *(const uint2*)(wb + (unsigned)o2 + colb);
        const uint2 a3 = *(const uint2*)(wb + (unsigned)o3 + colb);
        const uint2 a4 = *(const uint2*)(wb + (unsigned)o4 + colb);
        const uint2 a5 = *(const uint2*)(wb + (unsigned)o5 + colb);
        const uint2 a6 = *(const uint2*)(wb + (unsigned)o6 + colb);
        const uint2 a7 = *(const uint2*)(wb + (unsigned)o7 + colb);
        // nstm gathers
        const uint2 b0 = *(const uint2*)(wb + (unsigned)q0 + colb);
        const uint2 b1 = *(const uint2*)(wb + (unsigned)q1 + colb);
        const uint2 b2 = *(const uint2*)(wb + (unsigned)q2 + colb);
        const uint2 b3 = *(const uint2*)(wb + (unsigned)q3 + colb);
        const uint2 b4 = *(const uint2*)(wb + (unsigned)q4 + colb);
        const uint2 b5 = *(const uint2*)(wb + (unsigned)q5 + colb);
        const uint2 b6 = *(const uint2*)(wb + (unsigned)q6 + colb);
        const uint2 b7 = *(const uint2*)(wb + (unsigned)q7 + colb);
        __builtin_amdgcn_sched_barrier(0);   // keep 16 gathers in flight

        // bias-fold: acc = bias/4 - 128*sum(v*scale)
        const float corr_s = 128.f * (((vs0+vs1)+(vs2+vs3)) + ((vs4+vs5)+(vs6+vs7)));
        const float corr_n = 128.f * (((vn0+vn1)+(vn2+vn3)) + ((vn4+vn5)+(vn6+vn7)));

        float acc_s[8], acc_n[8];
        #pragma unroll
        for (int t = 0; t < 8; ++t) {
            acc_s[t] = bbq[t] - corr_s;
            acc_n[t] = bbq[t] - corr_n;
        }

        CONS_U8(acc_s, a0, vs0); CONS_U8(acc_s, a1, vs1);
        CONS_U8(acc_s, a2, vs2); CONS_U8(acc_s, a3, vs3);
        CONS_U8(acc_s, a4, vs4); CONS_U8(acc_s, a5, vs5);
        CONS_U8(acc_s, a6, vs6); CONS_U8(acc_s, a7, vs7);
        CONS_U8(acc_n, b0, vn0); CONS_U8(acc_n, b1, vn1);
        CONS_U8(acc_n, b2, vn2); CONS_U8(acc_n, b3, vn3);
        CONS_U8(acc_n, b4, vn4); CONS_U8(acc_n, b5, vn5);
        CONS_U8(acc_n, b6, vn6); CONS_U8(acc_n, b7, vn7);

        // fg-butterfly: 2 stages (lane bits 3,4)
        #pragma unroll
        for (int t = 0; t < 8; ++t) {
            acc_s[t] += __shfl_xor(acc_s[t], 8);
            acc_n[t] += __shfl_xor(acc_n[t], 8);
        }
        #pragma unroll
        for (int t = 0; t < 8; ++t) {
            acc_s[t] += __shfl_xor(acc_s[t], 16);
            acc_n[t] += __shfl_xor(acc_n[t], 16);
        }

        // clip + dot
        float part = 0.f;
        #pragma unroll
        for (int t = 0; t < 8; ++t) {
            const float hs = fminf(fmaxf(acc_s[t], 0.f), 1.f);
            part = fmaf(hs, wos[t], part);
        }
        #pragma unroll
        for (int t = 0; t < 8; ++t) {
            const float hn = fminf(fmaxf(acc_n[t], 0.f), 1.f);
            part = fmaf(hn, won[t], part);
        }
        part += __shfl_xor(part, 1);
        part += __shfl_xor(part, 2);
        part += __shfl_xor(part, 4);

        if ((lane & 31) == 0 && row_g < batch)
            partial[row_g * NCHUNK + c] = part;
    }
}

// ---------------------------------------------------------------------------
// Kernel 3: combine 8 chunk partials -> sigmoid
// ---------------------------------------------------------------------------
__global__ __launch_bounds__(256)
void final_out(const float* __restrict__ partial,
               const float* __restrict__ b_out,
               float* __restrict__ out, int batch)
{
    const int b = blockIdx.x * 256 + threadIdx.x;
    if (b >= batch) return;
    const float4 p0 = *(const float4*)(partial + b * NCHUNK);
    const float4 p1 = *(const float4*)(partial + b * NCHUNK + 4);
    const float tot = ((p0.x + p0.y) + (p0.z + p0.w))
                    + ((p1.x + p1.y) + (p1.z + p1.w)) + b_out[0];
    out[b] = 1.0f / (1.0f + expf(-tot));
}

// ---------------------------------------------------------------------------
// Fallback: no workspace needed (round-1 kernel).
// ---------------------------------------------------------------------------
__global__ __launch_bounds__(256)
void nnhalfka_fused(const int* __restrict__ stm_idx,
                    const int* __restrict__ nstm_idx,
                    const float* __restrict__ values,
                    const float* __restrict__ W_ft,
                    const float* __restrict__ b_ft,
                    const float* __restrict__ W_fft,
                    const float* __restrict__ b_fft,
                    const float* __restrict__ W_out,
                    const float* __restrict__ b_out,
                    float* __restrict__ out,
                    int nnz)
{
    const int b   = blockIdx.x;
    const int tid = threadIdx.x;

    __shared__ int   s_fs[MAXF], s_fsm[MAXF], s_fn[MAXF], s_fnm[MAXF];
    __shared__ float s_v[MAXF];
    __shared__ float s_red[4];

    if (tid < MAXF) {
        const int g  = b * MAXF + tid;
        const int fs = stm_idx[nnz + g];
        const int fn = nstm_idx[nnz + g];
        s_fs[tid]  = fs * FTOUT;
        s_fsm[tid] = (fs % VFT) * FTOUT;
        s_fn[tid]  = fn * FTOUT;
        s_fnm[tid] = (fn % VFT) * FTOUT;
        s_v[tid]   = values[g];
    }
    __syncthreads();

    const int j = tid * 2;
    float2 accs = make_float2(0.f, 0.f);
    float2 accn = make_float2(0.f, 0.f);

    #pragma unroll 4
    for (int k = 0; k < MAXF; ++k) {
        const float v    = s_v[k];
        const float2 ws  = *(const float2*)(W_ft  + s_fs[k]  + j);
        const float2 wfs = *(const float2*)(W_fft + s_fsm[k] + j);
        const float2 wn  = *(const float2*)(W_ft  + s_fn[k]  + j);
        const float2 wfn = *(const float2*)(W_fft + s_fnm[k] + j);
        accs.x += v * (ws.x + wfs.x);
        accs.y += v * (ws.y + wfs.y);
        accn.x += v * (wn.x + wfn.x);
        accn.y += v * (wn.y + wfn.y);
    }

    const float bb0 = b_ft[j]     + b_fft[j];
    const float bb1 = b_ft[j + 1] + b_fft[j + 1];
    const float hs0 = fminf(fmaxf(accs.x + bb0, 0.f), 1.f);
    const float hs1 = fminf(fmaxf(accs.y + bb1, 0.f), 1.f);
    const float hn0 = fminf(fmaxf(accn.x + bb0, 0.f), 1.f);
    const float hn1 = fminf(fmaxf(accn.y + bb1, 0.f), 1.f);

    float partial = hs0 * W_out[j]         + hs1 * W_out[j + 1]
                  + hn0 * W_out[FTOUT + j] + hn1 * W_out[FTOUT + j + 1];
    #pragma unroll
    for (int off = 32; off > 0; off >>= 1)
        partial += __shfl_down(partial, off);
    if ((tid & 63) == 0) s_red[tid >> 6] = partial;
    __syncthreads();
    if (tid == 0) {
        const float tot = s_red[0] + s_red[1] + s_red[2] + s_red[3] + b_out[0];
        out[b] = 1.0f / (1.0f + expf(-tot));
    }
}

extern "C" void kernel_launch(void* const* d_in, const int* in_sizes, int n_in,
                              void* d_out, int out_size, void* d_ws, size_t ws_size,
                              hipStream_t stream) {
    const int*   stm_idx  = (const int*)d_in[0];
    const int*   nstm_idx = (const int*)d_in[1];
    const float* values   = (const float*)d_in[2];
    const float* W_ft     = (const float*)d_in[4];
    const float* b_ft     = (const float*)d_in[5];
    const float* W_fft    = (const float*)d_in[6];
    const float* b_fft    = (const float*)d_in[7];
    const float* W_out    = (const float*)d_in[8];
    const float* b_out    = (const float*)d_in[9];
    float* out = (float*)d_out;

    const int nnz   = in_sizes[0] / 2;
    const int batch = out_size;

    const size_t WQ_B   = (size_t)FTIN * FTOUT;          // 25,165,824
    const size_t SC_B   = (size_t)FTIN * 4;              // 196,608
    const size_t OFF_B  = (size_t)batch * 64 * 2;
    const size_t VS_B   = (size_t)batch * 32 * 4;
    const size_t VN_B   = (size_t)batch * 32 * 4;
    const size_t PART_B = (size_t)batch * NCHUNK * 4;
    const size_t need = WQ_B + SC_B + OFF_B + VS_B + VN_B + PART_B;

    if (ws_size >= need && (batch % RPB) == 0) {
        char* p = (char*)d_ws;
        unsigned char*  Wq      = (unsigned char*)p;        p += WQ_B;
        float*          scale   = (float*)p;                p += SC_B;
        unsigned short* off16   = (unsigned short*)p;       p += OFF_B;
        float*          val_s   = (float*)p;                p += VS_B;
        float*          val_n   = (float*)p;                p += VN_B;
        float*          partial = (float*)p;

        build_q8<<<FTIN / 4, 256, 0, stream>>>(W_ft, W_fft, Wq, scale);
        prep_idx<<<(batch * 64 + 255) / 256, 256, 0, stream>>>(
            stm_idx, nstm_idx, values, scale, off16, val_s, val_n, nnz, batch);
        gather_q8<<<(batch / RPB) * NCHUNK, 256, 0, stream>>>(
            Wq, off16, val_s, val_n, b_ft, b_fft, W_out, partial, batch);
        final_out<<<(batch + 255) / 256, 256, 0, stream>>>(partial, b_out, out, batch);
    } else {
        nnhalfka_fused<<<batch, 256, 0, stream>>>(
            stm_idx, nstm_idx, values, W_ft, b_ft, W_fft, b_fft, W_out, b_out,
            out, nnz);
    }
}